// Round 7
// baseline (298.599 us; speedup 1.0000x reference)
//
#include <hip/hip_runtime.h>
#include <stdint.h>
#include <stddef.h>

// Problem constants (fixed by setup_inputs)
#define N_ROWS 500000
#define DDIM   128
#define K2     256      // 2*D
#define KBOND  32
#define TILE   32
#define NTL    (N_ROWS / TILE)    // 15625, exact
#define NBLK   768                // persistent pass1 blocks = 3 per CU
#define MR_BLKS 12                // 768 / 64
#define P2_BLOCKS 2048

typedef float  f32x4  __attribute__((ext_vector_type(4)));
typedef __bf16 bf16x8 __attribute__((ext_vector_type(8)));
typedef __bf16 bf16x4 __attribute__((ext_vector_type(4)));

// ---- module-scope device scratch ----
__device__ __bf16 g_wbf[DDIM * K2];                    // 64 KiB  W_i_w bf16 [d][k]
__device__ float  g_s[N_ROWS];                         // 2 MiB   s[n] = colsum(bond)
__device__ float  g_partials[NBLK * DDIM];             // 384 KiB
__device__ float  g_p2[MR_BLKS * DDIM];                // 6 KiB
__device__ float  g_msg[DDIM];
__device__ __bf16 g_hn[(size_t)N_ROWS * DDIM];         // 128 MiB h_n bf16

// raw barrier: lgkmcnt(0) only (ds_writes published), NO vmcnt drain.
// sched_barrier(0) fences pin ds_writes before / ds_reads after (rule #18).
#define BARSEQ() do {                                   \
    __builtin_amdgcn_sched_barrier(0);                  \
    asm volatile("s_waitcnt lgkmcnt(0)");               \
    __builtin_amdgcn_s_barrier();                       \
    __builtin_amdgcn_sched_barrier(0);                  \
  } while (0)

// ---- kernel 1: W_i_w f32 -> bf16 ----
__global__ void k_prep(const float* __restrict__ w) {
  int t = blockIdx.x * blockDim.x + threadIdx.x;
  if (t < DDIM * K2) g_wbf[t] = (__bf16)w[t];
}

// ---- kernel 1b: s[n] = sum_k bond[k][n]  (pure streaming, ~64 MB) ----
__global__ __launch_bounds__(256)
void k_s(const float* __restrict__ bond) {
  int n = blockIdx.x * 256 + threadIdx.x;
  if (n >= N_ROWS) return;
  float a = 0.f, b = 0.f;
  #pragma unroll
  for (int k = 0; k < KBOND; k += 2) {
    a += bond[(size_t)k * N_ROWS + n];
    b += bond[(size_t)(k + 1) * N_ROWS + n];
  }
  g_s[n] = a + b;
}

// ---- kernel 2: fused h_n GEMM + m partial accumulation ----
// Persistent: 768 blocks (3/CU) x 512 threads (8 waves); 32-row tiles.
// T14 async-STAGE split, now with the VGPR budget to actually hold it:
// __launch_bounds__(512,6) caps occupancy at 6 waves/SIMD -> VGPR cap ~85,
// so the 16 staged f32x4 regs stay live across the compute phase.
// Loop: issue loads(t+1) -> compute(t) from LDS -> epilogue stores ->
// cvt+ds_write(t+1 -> buf^1) [compiler emits exact vmcnt(4), stores NOT
// drained] -> raw s_barrier with lgkmcnt(0) only.
// LDS: R6's measured-zero-conflict bf16 layout. Row r (0..31) at r*512 B,
// byte(r,slot) = r*512 + (16*slot ^ ((r&15)<<4)); x = bytes [0,256) (k<128),
// he at +256. Read fragment (ks,g): byte (64ks+16g) ^ (l15<<4).
// MFMA swapped (A=W rows=d, B=data cols=n); A/B share the (g,e)->k map
// k = 32ks+8g+e, so any internal k-permutation cancels (verified R2-R6).
__global__ __launch_bounds__(512, 6)
void k_pass1(const float* __restrict__ x, const float* __restrict__ he,
             const float* __restrict__ bias)
{
  __shared__ __align__(16) unsigned char a_lds[2][TILE * 512];   // 2 x 16 KiB

  const int tid  = threadIdx.x;
  const int w    = tid >> 6;        // wave 0..7: owns d in [16w, 16w+16)
  const int lane = tid & 63;
  const int l15  = lane & 15;
  const int g    = lane >> 4;       // 0..3

  // W fragments, all K, in registers (loaded once): 32 VGPR
  bf16x8 wfrag[8];
  #pragma unroll
  for (int ks = 0; ks < 8; ++ks)
    wfrag[ks] = *(const bf16x8*)(g_wbf + (size_t)(16 * w + l15) * K2 + 32 * ks + 8 * g);

  const int d0 = 16 * w + 4 * g;
  const f32x4 bv = *(const f32x4*)(bias + d0);

  // staging coordinates: thread -> (row sr, 16B slot sc)
  const int sr = tid >> 4;                       // 0..31
  const int sc = tid & 15;                       // 0..15
  const unsigned swz   = (unsigned)((sr & 15) << 4);
  const unsigned wo_x  = (unsigned)(sr * 512) + ((16u * sc) ^ swz);
  const unsigned wo_he = (unsigned)(sr * 512) + 256u + ((16u * sc) ^ swz);
  const unsigned rsw   = (unsigned)(l15 << 4);   // read-side swizzle

  f32x4 macc = (f32x4)(0.f);

  int t = blockIdx.x;

  // ---- prologue: stage tile t into buf 0 ----
  {
    const float* xr = x  + (size_t)(t * TILE + sr) * DDIM + 8 * sc;
    const float* hr = he + (size_t)(t * TILE + sr) * DDIM + 8 * sc;
    f32x4 xa = *(const f32x4*)xr, xb = *(const f32x4*)(xr + 4);
    f32x4 ha = *(const f32x4*)hr, hb = *(const f32x4*)(hr + 4);
    bf16x8 bx, bh;
    #pragma unroll
    for (int i = 0; i < 4; ++i) {
      bx[i] = (__bf16)xa[i]; bx[4 + i] = (__bf16)xb[i];
      bh[i] = (__bf16)ha[i]; bh[4 + i] = (__bf16)hb[i];
    }
    *(bf16x8*)(&a_lds[0][wo_x])  = bx;
    *(bf16x8*)(&a_lds[0][wo_he]) = bh;
  }
  float s0 = g_s[t * TILE + l15];
  float s1 = g_s[t * TILE + 16 + l15];
  BARSEQ();

  int cur = 0;
  while (true) {
    const int  tn  = t + NBLK;
    const bool has = tn < NTL;
    const int  tl  = has ? tn : t;              // clamp: keep body single-BB

    // ---- early-issue next tile's global loads (held in registers) ----
    const float* xr = x  + (size_t)(tl * TILE + sr) * DDIM + 8 * sc;
    const float* hr = he + (size_t)(tl * TILE + sr) * DDIM + 8 * sc;
    f32x4 xa = *(const f32x4*)xr, xb = *(const f32x4*)(xr + 4);
    f32x4 ha = *(const f32x4*)hr, hb = *(const f32x4*)(hr + 4);
    float s0n = g_s[tl * TILE + l15];
    float s1n = g_s[tl * TILE + 16 + l15];
    __builtin_amdgcn_sched_barrier(0);

    // ---- compute tile t from buf[cur] ----
    f32x4 acc0 = (f32x4)(0.f), acc1 = (f32x4)(0.f);
    const unsigned char* base = &a_lds[cur][0];
    #pragma unroll
    for (int ks = 0; ks < 8; ++ks) {
      const unsigned o = (unsigned)(64 * ks + 16 * g);
      bf16x8 b0 = *(const bf16x8*)(base + l15 * 512        + (o ^ rsw));
      bf16x8 b1 = *(const bf16x8*)(base + (16 + l15) * 512 + (o ^ rsw));
      acc0 = __builtin_amdgcn_mfma_f32_16x16x32_bf16(wfrag[ks], b0, acc0, 0, 0, 0);
      acc1 = __builtin_amdgcn_mfma_f32_16x16x32_bf16(wfrag[ks], b1, acc1, 0, 0, 0);
    }

    // ---- epilogue tile t: bias+relu, m partial, h_n stores ----
    {
      const int rb = t * TILE;
      f32x4 h0, h1;
      #pragma unroll
      for (int i = 0; i < 4; ++i) {
        float a = acc0[i] + bv[i]; h0[i] = a > 0.f ? a : 0.f;
        float b = acc1[i] + bv[i]; h1[i] = b > 0.f ? b : 0.f;
      }
      #pragma unroll
      for (int i = 0; i < 4; ++i) macc[i] += s0 * h0[i] + s1 * h1[i];
      bf16x4 hb0, hb1;
      #pragma unroll
      for (int i = 0; i < 4; ++i) { hb0[i] = (__bf16)h0[i]; hb1[i] = (__bf16)h1[i]; }
      *(bf16x4*)(g_hn + (size_t)(rb + l15) * DDIM + d0)      = hb0;
      *(bf16x4*)(g_hn + (size_t)(rb + 16 + l15) * DDIM + d0) = hb1;
    }
    __builtin_amdgcn_sched_barrier(0);

    // ---- write staged regs into buf[cur^1] (compiler emits vmcnt(4)) ----
    {
      bf16x8 bx, bh;
      #pragma unroll
      for (int i = 0; i < 4; ++i) {
        bx[i] = (__bf16)xa[i]; bx[4 + i] = (__bf16)xb[i];
        bh[i] = (__bf16)ha[i]; bh[4 + i] = (__bf16)hb[i];
      }
      *(bf16x8*)(&a_lds[cur ^ 1][wo_x])  = bx;
      *(bf16x8*)(&a_lds[cur ^ 1][wo_he]) = bh;
    }
    BARSEQ();   // lgkmcnt(0) + s_barrier only -- h_n stores NOT drained

    if (!has) break;
    t = tn; cur ^= 1; s0 = s0n; s1 = s1n;
  }

  // ---- block partial for m: sum the 16 l15-lanes (same d0 quad) ----
  #pragma unroll
  for (int off = 1; off <= 8; off <<= 1) {
    #pragma unroll
    for (int i = 0; i < 4; ++i) macc[i] += __shfl_xor(macc[i], off, 64);
  }
  if (l15 == 0)
    *(f32x4*)(&g_partials[(size_t)blockIdx.x * DDIM + d0]) = macc;
}

// ---- kernel 3: parallel partial reduce: NBLK x 128 -> MR_BLKS x 128 ----
__global__ void k_mr() {
  const int d    = threadIdx.x & 127;
  const int half = threadIdx.x >> 7;        // 0/1
  const int r0   = blockIdx.x * 64;
  float acc = 0.f;
  for (int r = r0 + half; r < r0 + 64; r += 2)
    acc += g_partials[(size_t)r * DDIM + d];
  __shared__ float sp[DDIM];
  if (half == 0) sp[d] = acc;
  __syncthreads();
  if (half == 1) g_p2[blockIdx.x * DDIM + d] = sp[d] + acc;
}

// ---- kernel 4: m[d] = sum_c p2[c][d]; msg = W_m m + b_m ----
__global__ void k_msg(const float* __restrict__ wm, const float* __restrict__ bm) {
  __shared__ float ms[DDIM];
  const int d = threadIdx.x;                // 128 threads
  float s = 0.f;
  #pragma unroll
  for (int c = 0; c < MR_BLKS; ++c) s += g_p2[c * DDIM + d];
  ms[d] = s;
  __syncthreads();
  float acc = bm[d];
  #pragma unroll 8
  for (int j = 0; j < DDIM; ++j) acc += ms[j] * wm[(size_t)d * DDIM + j];
  g_msg[d] = acc;
}

// ---- kernel 5: out = relu(h_n + msg) ----
__global__ __launch_bounds__(256)
void k_pass2(float* __restrict__ out)
{
  __shared__ float ms[DDIM];
  if (threadIdx.x < DDIM) ms[threadIdx.x] = g_msg[threadIdx.x];
  __syncthreads();
  const size_t total = (size_t)N_ROWS * DDIM / 8;
  for (size_t c = (size_t)blockIdx.x * blockDim.x + threadIdx.x; c < total;
       c += (size_t)gridDim.x * blockDim.x) {
    const size_t base = c * 8;
    const int col0 = (int)(base & (DDIM - 1));
    bf16x8 hv = *(const bf16x8*)(g_hn + base);
    f32x4 o0, o1;
    #pragma unroll
    for (int i = 0; i < 4; ++i) {
      float a = (float)hv[i]     + ms[col0 + i];
      float b = (float)hv[4 + i] + ms[col0 + 4 + i];
      o0[i] = a > 0.f ? a : 0.f;
      o1[i] = b > 0.f ? b : 0.f;
    }
    *(f32x4*)(out + base)     = o0;
    *(f32x4*)(out + base + 4) = o1;
  }
}

extern "C" void kernel_launch(void* const* d_in, const int* in_sizes, int n_in,
                              void* d_out, int out_size, void* d_ws, size_t ws_size,
                              hipStream_t stream) {
  const float* x    = (const float*)d_in[0];
  const float* he   = (const float*)d_in[1];
  const float* bond = (const float*)d_in[2];
  const float* wi   = (const float*)d_in[3];
  const float* bi   = (const float*)d_in[4];
  const float* wm   = (const float*)d_in[5];
  const float* bm   = (const float*)d_in[6];
  float* out = (float*)d_out;
  (void)d_ws; (void)ws_size;

  k_prep<<<(DDIM * K2 + 255) / 256, 256, 0, stream>>>(wi);
  k_s<<<(N_ROWS + 255) / 256, 256, 0, stream>>>(bond);
  k_pass1<<<NBLK, 512, 0, stream>>>(x, he, bi);
  k_mr<<<MR_BLKS, 256, 0, stream>>>();
  k_msg<<<1, 128, 0, stream>>>(wm, bm);
  k_pass2<<<P2_BLOCKS, 256, 0, stream>>>(out);
}

// Round 8
// 281.170 us; speedup vs baseline: 1.0620x; 1.0620x over previous
//
#include <hip/hip_runtime.h>
#include <stdint.h>
#include <stddef.h>

// Problem constants (fixed by setup_inputs)
#define N_ROWS 500000
#define DDIM   128
#define K2     256      // 2*D
#define KBOND  32
#define TILE   16
#define NTL    (N_ROWS / TILE)    // 31250, exact (no tail)
#define NBLK   768                // persistent pass1 blocks = 3 per CU
#define MR_BLKS 12                // 768 / 64
#define P2_BLOCKS 2048

typedef float  f32x4  __attribute__((ext_vector_type(4)));
typedef __bf16 bf16x8 __attribute__((ext_vector_type(8)));
typedef __bf16 bf16x4 __attribute__((ext_vector_type(4)));

// ---- module-scope device scratch ----
__device__ __bf16 g_wbf[DDIM * K2];                    // 64 KiB  W_i_w bf16 [d][k]
__device__ float  g_s[N_ROWS];                         // 2 MiB   s[n] = colsum(bond)
__device__ float  g_partials[NBLK * DDIM];             // 384 KiB
__device__ float  g_p2[MR_BLKS * DDIM];                // 6 KiB
__device__ float  g_msg[DDIM];
__device__ __bf16 g_hn[(size_t)N_ROWS * DDIM];         // 128 MiB h_n bf16

// async global->LDS, 16 B per lane; dest must be wave-uniform (HW adds lane*16)
static __device__ __forceinline__ void gload16(const float* g, float* l) {
  __builtin_amdgcn_global_load_lds(
      (const __attribute__((address_space(1))) void*)g,
      (__attribute__((address_space(3))) void*)l, 16, 0, 0);
}

// ---- kernel 1: W_i_w f32 -> bf16 ----
__global__ void k_prep(const float* __restrict__ w) {
  int t = blockIdx.x * blockDim.x + threadIdx.x;
  if (t < DDIM * K2) g_wbf[t] = (__bf16)w[t];
}

// ---- kernel 1b: s[n] = sum_k bond[k][n]  (pure streaming, ~64 MB) ----
__global__ __launch_bounds__(256)
void k_s(const float* __restrict__ bond) {
  int n = blockIdx.x * 256 + threadIdx.x;
  if (n >= N_ROWS) return;
  float a = 0.f, b = 0.f;
  #pragma unroll
  for (int k = 0; k < KBOND; k += 2) {
    a += bond[(size_t)k * N_ROWS + n];
    b += bond[(size_t)(k + 1) * N_ROWS + n];
  }
  g_s[n] = a + b;
}

// ---- kernel 2: fused h_n GEMM + m partial accumulation ----
// Persistent: 768 blocks (3/CU) x 512 threads (8 waves); 16-row tiles.
// Staging: global_load_lds direct to f32 LDS (ZERO staging registers -- the
// R7 spill fix), double-buffered. Counted vmcnt(1) at a raw s_barrier: the 2
// stage-loads + g_s load are proven complete while the single h_n store rides
// across the barrier (never drained in-loop). No lgkm wait needed at the
// barrier (no ds_writes; ds_reads complete by use).
// LDS: row r (0..15) at r*1024 B, 16-B slots s=0..63 ([x | he] halves);
// phys slot = s ^ (r&7), realized as linear LDS dest + pre-swizzled global
// source col (G21). Reads address logical slots directly: addrA holds frag
// elems 0-3, addrA^16 holds elems 4-7 (s0 even) -- no descramble needed.
// b128 conflict check (16-lane quarters, g fixed): slot^ (l15&7) spans 8
// bank-groups, 2 lanes each = free (matches R4/R6 measured-zero layout).
// MFMA swapped (A=W rows=d, B=data cols=n); A/B share the (g,e)->k map
// k = 32ks+8g+e, so any internal k-permutation cancels (verified R2-R7).
__global__ __launch_bounds__(512, 6)
void k_pass1(const float* __restrict__ x, const float* __restrict__ he,
             const float* __restrict__ bias)
{
  __shared__ __align__(1024) float a_lds[2][TILE * K2];   // 2 x 16 KiB

  const int tid  = threadIdx.x;
  const int w    = tid >> 6;        // wave 0..7: owns d in [16w, 16w+16)
  const int lane = tid & 63;
  const int l15  = lane & 15;
  const int g    = lane >> 4;       // 0..3

  // W fragments, all K, in registers (loaded once): 32 VGPR
  bf16x8 wfrag[8];
  #pragma unroll
  for (int ks = 0; ks < 8; ++ks)
    wfrag[ks] = *(const bf16x8*)(g_wbf + (size_t)(16 * w + l15) * K2 + 32 * ks + 8 * g);

  const int d0 = 16 * w + 4 * g;
  const f32x4 bv = *(const f32x4*)(bias + d0);

  // staging source geometry: issue j stages row r = 2w+j; lane supplies
  // logical slot sl = lane ^ (r&7); sl<32 -> x cols [4sl,4sl+4), else he.
  int   soff[2];                     // f32 offset within the 256-f32 row
  const float* sarr[2];
  #pragma unroll
  for (int j = 0; j < 2; ++j) {
    const int r  = 2 * w + j;
    const int sl = lane ^ (r & 7);
    sarr[j] = (sl < 32) ? x : he;
    soff[j] = (sl < 32) ? 4 * sl : 4 * sl - 128;
  }

  f32x4 macc = (f32x4)(0.f);
  int t = blockIdx.x;

  // ---- prologue: stage tile t into buf 0, full drain once ----
  #pragma unroll
  for (int j = 0; j < 2; ++j)
    gload16(sarr[j] + (size_t)(t * TILE + 2 * w + j) * DDIM + soff[j],
            &a_lds[0][(2 * w + j) * K2]);
  float s0 = g_s[t * TILE + l15];
  __builtin_amdgcn_sched_barrier(0);
  asm volatile("s_waitcnt vmcnt(0)");
  __builtin_amdgcn_s_barrier();
  __builtin_amdgcn_sched_barrier(0);

  int cur = 0;
  while (true) {
    const int  tn  = t + NBLK;
    const bool has = tn < NTL;
    const int  tl  = has ? tn : t;              // clamp: keep body single-BB

    // ---- issue next tile's staging into buf^1 (no registers held) ----
    #pragma unroll
    for (int j = 0; j < 2; ++j)
      gload16(sarr[j] + (size_t)(tl * TILE + 2 * w + j) * DDIM + soff[j],
              &a_lds[cur ^ 1][(2 * w + j) * K2]);
    float s0n = g_s[tl * TILE + l15];
    __builtin_amdgcn_sched_barrier(0);

    // ---- compute tile t from buf[cur]: cvt-on-read + MFMA ----
    f32x4 acc = (f32x4)(0.f);
    const char* base = (const char*)&a_lds[cur][0];
    const unsigned rowb = (unsigned)(l15 * 1024);
    const unsigned p    = (unsigned)(l15 & 7);
    #pragma unroll
    for (int ks = 0; ks < 8; ++ks) {
      const unsigned sA = (unsigned)(8 * ks + 2 * g);          // even
      const unsigned aA = rowb + 16u * (sA ^ p);
      f32x4 A = *(const f32x4*)(base + aA);
      f32x4 B = *(const f32x4*)(base + (aA ^ 16u));
      bf16x8 b;
      #pragma unroll
      for (int i = 0; i < 4; ++i) { b[i] = (__bf16)A[i]; b[4 + i] = (__bf16)B[i]; }
      acc = __builtin_amdgcn_mfma_f32_16x16x32_bf16(wfrag[ks], b, acc, 0, 0, 0);
    }

    // ---- epilogue tile t: bias+relu, m partial, one 8-B h_n store ----
    {
      f32x4 h;
      #pragma unroll
      for (int i = 0; i < 4; ++i) {
        float v = acc[i] + bv[i]; h[i] = v > 0.f ? v : 0.f;
      }
      #pragma unroll
      for (int i = 0; i < 4; ++i) macc[i] += s0 * h[i];
      bf16x4 hb;
      #pragma unroll
      for (int i = 0; i < 4; ++i) hb[i] = (__bf16)h[i];
      *(bf16x4*)(g_hn + (size_t)(t * TILE + l15) * DDIM + d0) = hb;
    }

    // ---- counted-wait barrier: stage loads landed, store still in flight --
    __builtin_amdgcn_sched_barrier(0);
    asm volatile("s_waitcnt vmcnt(1)");
    __builtin_amdgcn_s_barrier();
    __builtin_amdgcn_sched_barrier(0);

    if (!has) break;
    t = tn; cur ^= 1; s0 = s0n;
  }

  // ---- block partial for m: sum the 16 l15-lanes (same d0 quad) ----
  #pragma unroll
  for (int off = 1; off <= 8; off <<= 1) {
    #pragma unroll
    for (int i = 0; i < 4; ++i) macc[i] += __shfl_xor(macc[i], off, 64);
  }
  if (l15 == 0)
    *(f32x4*)(&g_partials[(size_t)blockIdx.x * DDIM + d0]) = macc;
}

// ---- kernel 3: parallel partial reduce: NBLK x 128 -> MR_BLKS x 128 ----
__global__ void k_mr() {
  const int d    = threadIdx.x & 127;
  const int half = threadIdx.x >> 7;        // 0/1
  const int r0   = blockIdx.x * 64;
  float acc = 0.f;
  for (int r = r0 + half; r < r0 + 64; r += 2)
    acc += g_partials[(size_t)r * DDIM + d];
  __shared__ float sp[DDIM];
  if (half == 0) sp[d] = acc;
  __syncthreads();
  if (half == 1) g_p2[blockIdx.x * DDIM + d] = sp[d] + acc;
}

// ---- kernel 4: m[d] = sum_c p2[c][d]; msg = W_m m + b_m ----
__global__ void k_msg(const float* __restrict__ wm, const float* __restrict__ bm) {
  __shared__ float ms[DDIM];
  const int d = threadIdx.x;                // 128 threads
  float s = 0.f;
  #pragma unroll
  for (int c = 0; c < MR_BLKS; ++c) s += g_p2[c * DDIM + d];
  ms[d] = s;
  __syncthreads();
  float acc = bm[d];
  #pragma unroll 8
  for (int j = 0; j < DDIM; ++j) acc += ms[j] * wm[(size_t)d * DDIM + j];
  g_msg[d] = acc;
}

// ---- kernel 5: out = relu(h_n + msg) ----
__global__ __launch_bounds__(256)
void k_pass2(float* __restrict__ out)
{
  __shared__ float ms[DDIM];
  if (threadIdx.x < DDIM) ms[threadIdx.x] = g_msg[threadIdx.x];
  __syncthreads();
  const size_t total = (size_t)N_ROWS * DDIM / 8;
  for (size_t c = (size_t)blockIdx.x * blockDim.x + threadIdx.x; c < total;
       c += (size_t)gridDim.x * blockDim.x) {
    const size_t base = c * 8;
    const int col0 = (int)(base & (DDIM - 1));
    bf16x8 hv = *(const bf16x8*)(g_hn + base);
    f32x4 o0, o1;
    #pragma unroll
    for (int i = 0; i < 4; ++i) {
      float a = (float)hv[i]     + ms[col0 + i];
      float b = (float)hv[4 + i] + ms[col0 + 4 + i];
      o0[i] = a > 0.f ? a : 0.f;
      o1[i] = b > 0.f ? b : 0.f;
    }
    *(f32x4*)(out + base)     = o0;
    *(f32x4*)(out + base + 4) = o1;
  }
}

extern "C" void kernel_launch(void* const* d_in, const int* in_sizes, int n_in,
                              void* d_out, int out_size, void* d_ws, size_t ws_size,
                              hipStream_t stream) {
  const float* x    = (const float*)d_in[0];
  const float* he   = (const float*)d_in[1];
  const float* bond = (const float*)d_in[2];
  const float* wi   = (const float*)d_in[3];
  const float* bi   = (const float*)d_in[4];
  const float* wm   = (const float*)d_in[5];
  const float* bm   = (const float*)d_in[6];
  float* out = (float*)d_out;
  (void)d_ws; (void)ws_size;

  k_prep<<<(DDIM * K2 + 255) / 256, 256, 0, stream>>>(wi);
  k_s<<<(N_ROWS + 255) / 256, 256, 0, stream>>>(bond);
  k_pass1<<<NBLK, 512, 0, stream>>>(x, he, bi);
  k_mr<<<MR_BLKS, 256, 0, stream>>>();
  k_msg<<<1, 128, 0, stream>>>(wm, bm);
  k_pass2<<<P2_BLOCKS, 256, 0, stream>>>(out);
}

// Round 9
// 264.284 us; speedup vs baseline: 1.1298x; 1.0639x over previous
//
#include <hip/hip_runtime.h>
#include <stdint.h>
#include <stddef.h>

// Problem constants (fixed by setup_inputs)
#define N_ROWS 500000
#define DDIM   128
#define K2     256      // 2*D
#define KBOND  32
#define TILE   16
#define NTL    (N_ROWS / TILE)    // 31250, exact (no tail)
#define NBLK   768                // persistent pass1 blocks = 3 per CU
#define MR_BLKS 12                // 768 / 64
#define P2_BLOCKS 2048

typedef float  f32x4  __attribute__((ext_vector_type(4)));
typedef __bf16 bf16x8 __attribute__((ext_vector_type(8)));
typedef __bf16 bf16x4 __attribute__((ext_vector_type(4)));

// ---- module-scope device scratch ----
__device__ __bf16 g_wbf[DDIM * K2];                    // 64 KiB  W_i_w bf16 [d][k]
__device__ float  g_s[N_ROWS];                         // 2 MiB   s[n] = colsum(bond)
__device__ float  g_partials[NBLK * DDIM];             // 384 KiB
__device__ float  g_p2[MR_BLKS * DDIM];                // 6 KiB
__device__ float  g_msg[DDIM];
__device__ __bf16 g_hn[(size_t)N_ROWS * DDIM];         // 128 MiB h_n bf16

// ---- kernel 1: W_i_w f32 -> bf16 ----
__global__ void k_prep(const float* __restrict__ w) {
  int t = blockIdx.x * blockDim.x + threadIdx.x;
  if (t < DDIM * K2) g_wbf[t] = (__bf16)w[t];
}

// ---- kernel 1b: s[n] = sum_k bond[k][n]  (pure streaming, ~64 MB) ----
__global__ __launch_bounds__(256)
void k_s(const float* __restrict__ bond) {
  int n = blockIdx.x * 256 + threadIdx.x;
  if (n >= N_ROWS) return;
  float a = 0.f, b = 0.f;
  #pragma unroll
  for (int k = 0; k < KBOND; k += 2) {
    a += bond[(size_t)k * N_ROWS + n];
    b += bond[(size_t)(k + 1) * N_ROWS + n];
  }
  g_s[n] = a + b;
}

// ---- kernel 2: fused h_n GEMM + m partial accumulation ----
// LDS-bandwidth-aware version. 256 threads = 4 waves; wave w owns d in
// [32w, 32w+32) (wfrag[2][8] in regs, 64 VGPR) so ONE ds_read_b128 B-frag
// feeds TWO MFMAs, and only 4 waves re-read the tile: LDS reads per 16-row
// tile = 4 x 8 KB = 32 KB (was 128 KB in R8) -> ~1.0 GB total, off the
// critical path. bf16 in LDS, R6's measured-ZERO-conflict layout:
//   row r (0..15) at r*512 B; 16-B slot s at byte (16 s) ^ ((r&15)<<4);
//   x = slots 0-15 (k<128), he = slots 16-31. Global loads stay linear.
// T14 async-STAGE split (issue loads(t+1) -> compute(t) -> cvt+ds_write),
// counted barrier: lgkmcnt(0)+s_barrier only; h_n stores ride across; the
// compiler's auto-vmcnt covers staged-load -> ds_write deps.
// __launch_bounds__(256,3): VGPR cap ~170 >= live ~125 -> no R7-style spill,
// staged regs provably held. 3 blocks/CU stagger to cover HBM latency.
// MFMA swapped (A=W rows=d, B=data cols=n); A/B share the (g,e)->k map
// k = 32ks+8g+e, so any internal k-permutation cancels (verified R2-R8).
__global__ __launch_bounds__(256, 3)
void k_pass1(const float* __restrict__ x, const float* __restrict__ he,
             const float* __restrict__ bias)
{
  __shared__ __align__(16) unsigned char a_lds[2][TILE * 512];   // 2 x 8 KiB

  const int tid  = threadIdx.x;
  const int w    = tid >> 6;        // wave 0..3: owns d in [32w, 32w+32)
  const int lane = tid & 63;
  const int l15  = lane & 15;
  const int g    = lane >> 4;       // 0..3

  // W fragments for 2 d-groups, all K, in registers: 64 VGPR
  bf16x8 wfrag[2][8];
  #pragma unroll
  for (int dg = 0; dg < 2; ++dg)
    #pragma unroll
    for (int ks = 0; ks < 8; ++ks)
      wfrag[dg][ks] = *(const bf16x8*)(g_wbf +
          (size_t)(32 * w + 16 * dg + l15) * K2 + 32 * ks + 8 * g);

  f32x4 bv0 = *(const f32x4*)(bias + 32 * w + 4 * g);
  f32x4 bv1 = *(const f32x4*)(bias + 32 * w + 16 + 4 * g);

  // staging coords: thread -> (row sr, slot sc); x slot sc, he slot sc+16
  const int sr = tid >> 4;                       // 0..15
  const int sc = tid & 15;                       // 0..15
  const unsigned swz   = (unsigned)(sr << 4);
  const unsigned wo_x  = (unsigned)(sr * 512) + ((16u * sc) ^ swz);
  const unsigned wo_he = (unsigned)(sr * 512) + ((256u + 16u * sc) ^ swz);
  const unsigned rsw   = (unsigned)(l15 << 4);   // read-side swizzle

  f32x4 macc0 = (f32x4)(0.f), macc1 = (f32x4)(0.f);
  int t = blockIdx.x;

  // ---- prologue: stage tile t into buf 0 ----
  {
    const float* xr = x  + (size_t)(t * TILE + sr) * DDIM + 8 * sc;
    const float* hr = he + (size_t)(t * TILE + sr) * DDIM + 8 * sc;
    f32x4 xa = *(const f32x4*)xr, xb = *(const f32x4*)(xr + 4);
    f32x4 ha = *(const f32x4*)hr, hb = *(const f32x4*)(hr + 4);
    bf16x8 bx, bh;
    #pragma unroll
    for (int i = 0; i < 4; ++i) {
      bx[i] = (__bf16)xa[i]; bx[4 + i] = (__bf16)xb[i];
      bh[i] = (__bf16)ha[i]; bh[4 + i] = (__bf16)hb[i];
    }
    *(bf16x8*)(&a_lds[0][wo_x])  = bx;
    *(bf16x8*)(&a_lds[0][wo_he]) = bh;
  }
  float s0 = g_s[t * TILE + l15];
  __builtin_amdgcn_sched_barrier(0);
  asm volatile("s_waitcnt lgkmcnt(0)");
  __builtin_amdgcn_s_barrier();
  __builtin_amdgcn_sched_barrier(0);

  int cur = 0;
  while (true) {
    const int  tn  = t + NBLK;
    const bool has = tn < NTL;
    const int  tl  = has ? tn : t;              // clamp: keep body single-BB

    // ---- early-issue next tile's global loads (held in registers) ----
    const float* xr = x  + (size_t)(tl * TILE + sr) * DDIM + 8 * sc;
    const float* hr = he + (size_t)(tl * TILE + sr) * DDIM + 8 * sc;
    f32x4 xa = *(const f32x4*)xr, xb = *(const f32x4*)(xr + 4);
    f32x4 ha = *(const f32x4*)hr, hb = *(const f32x4*)(hr + 4);
    float s0n = g_s[tl * TILE + l15];
    __builtin_amdgcn_sched_barrier(0);

    // ---- compute tile t from buf[cur]: 8 ds_read_b128, 16 MFMA ----
    f32x4 acc0 = (f32x4)(0.f), acc1 = (f32x4)(0.f);
    const unsigned char* base = &a_lds[cur][0];
    #pragma unroll
    for (int ks = 0; ks < 8; ++ks) {
      const unsigned o = (unsigned)(64 * ks + 16 * g);
      bf16x8 b = *(const bf16x8*)(base + l15 * 512 + (o ^ rsw));
      acc0 = __builtin_amdgcn_mfma_f32_16x16x32_bf16(wfrag[0][ks], b, acc0, 0, 0, 0);
      acc1 = __builtin_amdgcn_mfma_f32_16x16x32_bf16(wfrag[1][ks], b, acc1, 0, 0, 0);
    }

    // ---- epilogue tile t: bias+relu, m partial, two 8-B h_n stores ----
    {
      const int n = t * TILE + l15;
      f32x4 h0, h1;
      #pragma unroll
      for (int i = 0; i < 4; ++i) {
        float a = acc0[i] + bv0[i]; h0[i] = a > 0.f ? a : 0.f;
        float b = acc1[i] + bv1[i]; h1[i] = b > 0.f ? b : 0.f;
      }
      #pragma unroll
      for (int i = 0; i < 4; ++i) { macc0[i] += s0 * h0[i]; macc1[i] += s0 * h1[i]; }
      bf16x4 hb0, hb1;
      #pragma unroll
      for (int i = 0; i < 4; ++i) { hb0[i] = (__bf16)h0[i]; hb1[i] = (__bf16)h1[i]; }
      *(bf16x4*)(g_hn + (size_t)n * DDIM + 32 * w + 4 * g)      = hb0;
      *(bf16x4*)(g_hn + (size_t)n * DDIM + 32 * w + 16 + 4 * g) = hb1;
    }
    __builtin_amdgcn_sched_barrier(0);

    // ---- cvt staged regs -> ds_write buf[cur^1] (auto-vmcnt covers deps) --
    {
      bf16x8 bx, bh;
      #pragma unroll
      for (int i = 0; i < 4; ++i) {
        bx[i] = (__bf16)xa[i]; bx[4 + i] = (__bf16)xb[i];
        bh[i] = (__bf16)ha[i]; bh[4 + i] = (__bf16)hb[i];
      }
      *(bf16x8*)(&a_lds[cur ^ 1][wo_x])  = bx;
      *(bf16x8*)(&a_lds[cur ^ 1][wo_he]) = bh;
    }
    __builtin_amdgcn_sched_barrier(0);
    asm volatile("s_waitcnt lgkmcnt(0)");
    __builtin_amdgcn_s_barrier();
    __builtin_amdgcn_sched_barrier(0);

    if (!has) break;
    t = tn; cur ^= 1; s0 = s0n;
  }

  // ---- block partial for m: sum the 16 l15-lanes (same d quad) ----
  #pragma unroll
  for (int off = 1; off <= 8; off <<= 1) {
    #pragma unroll
    for (int i = 0; i < 4; ++i) {
      macc0[i] += __shfl_xor(macc0[i], off, 64);
      macc1[i] += __shfl_xor(macc1[i], off, 64);
    }
  }
  if (l15 == 0) {
    *(f32x4*)(&g_partials[(size_t)blockIdx.x * DDIM + 32 * w + 4 * g])      = macc0;
    *(f32x4*)(&g_partials[(size_t)blockIdx.x * DDIM + 32 * w + 16 + 4 * g]) = macc1;
  }
}

// ---- kernel 3: parallel partial reduce: NBLK x 128 -> MR_BLKS x 128 ----
__global__ void k_mr() {
  const int d    = threadIdx.x & 127;
  const int half = threadIdx.x >> 7;        // 0/1
  const int r0   = blockIdx.x * 64;
  float acc = 0.f;
  for (int r = r0 + half; r < r0 + 64; r += 2)
    acc += g_partials[(size_t)r * DDIM + d];
  __shared__ float sp[DDIM];
  if (half == 0) sp[d] = acc;
  __syncthreads();
  if (half == 1) g_p2[blockIdx.x * DDIM + d] = sp[d] + acc;
}

// ---- kernel 4: m[d] = sum_c p2[c][d]; msg = W_m m + b_m ----
__global__ void k_msg(const float* __restrict__ wm, const float* __restrict__ bm) {
  __shared__ float ms[DDIM];
  const int d = threadIdx.x;                // 128 threads
  float s = 0.f;
  #pragma unroll
  for (int c = 0; c < MR_BLKS; ++c) s += g_p2[c * DDIM + d];
  ms[d] = s;
  __syncthreads();
  float acc = bm[d];
  #pragma unroll 8
  for (int j = 0; j < DDIM; ++j) acc += ms[j] * wm[(size_t)d * DDIM + j];
  g_msg[d] = acc;
}

// ---- kernel 5: out = relu(h_n + msg) ----
__global__ __launch_bounds__(256)
void k_pass2(float* __restrict__ out)
{
  __shared__ float ms[DDIM];
  if (threadIdx.x < DDIM) ms[threadIdx.x] = g_msg[threadIdx.x];
  __syncthreads();
  const size_t total = (size_t)N_ROWS * DDIM / 8;
  for (size_t c = (size_t)blockIdx.x * blockDim.x + threadIdx.x; c < total;
       c += (size_t)gridDim.x * blockDim.x) {
    const size_t base = c * 8;
    const int col0 = (int)(base & (DDIM - 1));
    bf16x8 hv = *(const bf16x8*)(g_hn + base);
    f32x4 o0, o1;
    #pragma unroll
    for (int i = 0; i < 4; ++i) {
      float a = (float)hv[i]     + ms[col0 + i];
      float b = (float)hv[4 + i] + ms[col0 + 4 + i];
      o0[i] = a > 0.f ? a : 0.f;
      o1[i] = b > 0.f ? b : 0.f;
    }
    *(f32x4*)(out + base)     = o0;
    *(f32x4*)(out + base + 4) = o1;
  }
}

extern "C" void kernel_launch(void* const* d_in, const int* in_sizes, int n_in,
                              void* d_out, int out_size, void* d_ws, size_t ws_size,
                              hipStream_t stream) {
  const float* x    = (const float*)d_in[0];
  const float* he   = (const float*)d_in[1];
  const float* bond = (const float*)d_in[2];
  const float* wi   = (const float*)d_in[3];
  const float* bi   = (const float*)d_in[4];
  const float* wm   = (const float*)d_in[5];
  const float* bm   = (const float*)d_in[6];
  float* out = (float*)d_out;
  (void)d_ws; (void)ws_size;

  k_prep<<<(DDIM * K2 + 255) / 256, 256, 0, stream>>>(wi);
  k_s<<<(N_ROWS + 255) / 256, 256, 0, stream>>>(bond);
  k_pass1<<<NBLK, 256, 0, stream>>>(x, he, bi);
  k_mr<<<MR_BLKS, 256, 0, stream>>>();
  k_msg<<<1, 128, 0, stream>>>(wm, bm);
  k_pass2<<<P2_BLOCKS, 256, 0, stream>>>(out);
}